// Round 4
// baseline (11112.744 us; speedup 1.0000x reference)
//
#include <hip/hip_runtime.h>
#include <stdint.h>

#define BSZ  128
#define TLEN 8192
#define MDIM 64
#define SDIM 512
#define NEG_BIG (-1e30f)

// ---- 8-bit dot product: 4 MACs per instruction, exact i32 accumulation ----
#if __has_builtin(__builtin_amdgcn_udot4)
  #define QA 255
  __device__ __forceinline__ int dot4(unsigned a, unsigned b, int c) {
    return (int)__builtin_amdgcn_udot4(a, b, (unsigned)c, false);
  }
#elif __has_builtin(__builtin_amdgcn_sdot4)
  #define QA 127   // keep bytes in [0,127] so signed == unsigned
  __device__ __forceinline__ int dot4(unsigned a, unsigned b, int c) {
    return __builtin_amdgcn_sdot4((int)a, (int)b, c, false);
  }
#else
  #define QA 255
  __device__ __forceinline__ int dot4(unsigned a, unsigned b, int c) {
    c += (int)((a & 0xffu) * (b & 0xffu));
    c += (int)(((a >> 8) & 0xffu) * ((b >> 8) & 0xffu));
    c += (int)(((a >> 16) & 0xffu) * ((b >> 16) & 0xffu));
    c += (int)((a >> 24) * (b >> 24));
    return c;
  }
#endif

// Wave-wide (64-lane) max via DPP, no LDS. Verified in R3 (absmax 0).
__device__ __forceinline__ float wave_max_f32(float x) {
  int v = __builtin_bit_cast(int, x);
#define DPP_STEP(ctrl)                                                        \
  {                                                                           \
    int o = __builtin_amdgcn_update_dpp(v, v, ctrl, 0xf, 0xf, false);         \
    v = __builtin_bit_cast(int, fmaxf(__builtin_bit_cast(float, v),           \
                                      __builtin_bit_cast(float, o)));         \
  }
  DPP_STEP(0x111)  // row_shr:1
  DPP_STEP(0x112)  // row_shr:2
  DPP_STEP(0x114)  // row_shr:4
  DPP_STEP(0x118)  // row_shr:8
  DPP_STEP(0x142)  // row_bcast15
  DPP_STEP(0x143)  // row_bcast31 -> lane63 has max(0..63)
#undef DPP_STEP
  return __builtin_bit_cast(float, __builtin_amdgcn_readlane(v, 63));
}

// Extract symbol index from one-hot rows: sym[b,t] = argmax_m x[b,t,m]
__global__ void sym_kernel(const float* __restrict__ x, uint8_t* __restrict__ sym) {
  int i = blockIdx.x * blockDim.x + threadIdx.x;  // flat (b,t)
  const float4* p = (const float4*)(x + (size_t)i * MDIM);
  int idx = 0;
  #pragma unroll
  for (int j = 0; j < 16; ++j) {
    float4 v = p[j];
    if (v.x > 0.5f) idx = 4*j + 0;
    if (v.y > 0.5f) idx = 4*j + 1;
    if (v.z > 0.5f) idx = 4*j + 2;
    if (v.w > 0.5f) idx = 4*j + 3;
  }
  sym[i] = (uint8_t)idx;
}

// Per-column max of A (quantization scale). One 64-thread block per column.
__global__ void colmax_kernel(const float* __restrict__ A, float* __restrict__ cmax) {
  int c = blockIdx.x, l = threadIdx.x;
  float m = 0.f;
  for (int r = l; r < SDIM; r += 64) m = fmaxf(m, A[(size_t)r * SDIM + c]);
  #pragma unroll
  for (int off = 32; off; off >>= 1) m = fmaxf(m, __shfl_xor(m, off));
  if (l == 0) cmax[c] = m;
}

// Pack A column-major as u8 row-quads: Aq[c*128 + j] = A[4j..4j+3][c] scaled
__global__ void pack_kernel(const float* __restrict__ A, const float* __restrict__ cmax,
                            unsigned* __restrict__ Aq) {
  int id = blockIdx.x * 256 + threadIdx.x;   // 512*128 = 65536 ids
  int c = id >> 7, j = id & 127;
  float s = (float)QA / cmax[c];
  unsigned q = 0;
  #pragma unroll
  for (int bb = 0; bb < 4; ++bb) {
    float v = A[(size_t)(4 * j + bb) * SDIM + c];
    int qi = (int)(v * s + 0.5f);
    if (qi > QA) qi = QA;
    q |= (unsigned)qi << (8 * bb);
  }
  Aq[c * 128 + j] = q;
}

// One block per batch; 1024 threads. Thread (c = t&511, h = t>>9) owns
// column c rows [256h, 256h+256) as 64 packed u8 VGPRs. h=0 threads also
// own state c's alpha (max/quant/combine). 2 barriers per step.
__global__ __launch_bounds__(1024, 4) void hmm_fwd(
    const unsigned* __restrict__ Aq, const float* __restrict__ cmax,
    const float* __restrict__ Bm, const uint8_t* __restrict__ sym,
    float* __restrict__ out) {
  const int b  = blockIdx.x;
  const int t  = threadIdx.x;
  const int c  = t & (SDIM - 1);
  const int h  = t >> 9;             // half 0/1: rows 256h..256h+255
  const int wv = t >> 6;             // wave 0..15

  __shared__ uint8_t p8[2][SDIM];    // quantized p, double-buffered
  __shared__ float   red[2][8];      // per-wave maxes (source waves 0..7)
  __shared__ float   part[SDIM];     // h=1 half-column partials (rescaled)
  __shared__ float   red2[8];

  // ---- this thread's A half-column: 64 packed words in VGPRs ----
  unsigned Areg[64];
  {
    const uint4* src = (const uint4*)(Aq + (size_t)c * 128 + 64 * h);
    #pragma unroll
    for (int j4 = 0; j4 < 16; ++j4) {
      uint4 v = src[j4];
      Areg[4*j4+0] = v.x; Areg[4*j4+1] = v.y;
      Areg[4*j4+2] = v.z; Areg[4*j4+3] = v.w;
    }
  }
  const float cscale = cmax[c] * (1.0f / ((float)QA * (float)QA));
  const uint8_t* symb = sym + (size_t)b * TLEN;

  // ---- init: alpha0 = log(B[sym0,:]+eps) + [0,-inf,...] (h=0 only) ----
  float alphaReg = NEG_BIG;
  int   symNext  = 0;
  float logE_cur = 0.f;
  if (h == 0) {
    int s0 = symb[0];
    alphaReg = __logf(Bm[s0 * SDIM + c] + 1e-16f) + (c == 0 ? 0.f : NEG_BIG);
    symNext  = symb[1];
    logE_cur = __logf(Bm[symNext * SDIM + c] + 1e-16f);
    symNext  = symb[2];
  }

  for (int step = 1; step < TLEN; ++step) {
    const int par = step & 1;

    // ---- pre-B1: h=0 waves quantize their 64 states with wave-local max ----
    if (h == 0) {
      float m_w = wave_max_f32(alphaReg);
      float p   = __expf(alphaReg - m_w);
      p8[par][c] = (uint8_t)(p * (float)QA + 0.5f);
      if ((t & 63) == 0) red[par][wv] = m_w;
    }
    __syncthreads();                  // B1: p8 + red ready

    // emission prefetch (h=0), hides under dot phase
    float eNxt = 0.f; int symNN = 0;
    if (h == 0) {
      eNxt  = Bm[symNext * SDIM + c];
      symNN = symb[(step + 2 <= TLEN - 1) ? step + 2 : TLEN - 1];
    }

    float4 ra = *(const float4*)&red[par][0];
    float4 rb = *(const float4*)&red[par][4];
    float mref = fmaxf(fmaxf(fmaxf(ra.x, ra.y), fmaxf(ra.z, ra.w)),
                       fmaxf(fmaxf(rb.x, rb.y), fmaxf(rb.z, rb.w)));
    // rescale factors for this half's 4 source waves
    float e0, e1, e2, e3;
    if (h == 0) { e0 = __expf(ra.x - mref); e1 = __expf(ra.y - mref);
                  e2 = __expf(ra.z - mref); e3 = __expf(ra.w - mref); }
    else        { e0 = __expf(rb.x - mref); e1 = __expf(rb.y - mref);
                  e2 = __expf(rb.z - mref); e3 = __expf(rb.w - mref); }

    // ---- dot: 64 dot4 over this half-column, 4 per-source-wave accs ----
    const uint32_t* pw = (const uint32_t*)p8[par] + 64 * h;  // wave-uniform
    float pr = 0.f;
    #pragma unroll
    for (int g = 0; g < 4; ++g) {
      int a = 0;
      #pragma unroll
      for (int q = 0; q < 4; ++q) {
        uint4 P = *(const uint4*)(pw + 16 * g + 4 * q);
        a = dot4(P.x, Areg[16*g + 4*q + 0], a);
        a = dot4(P.y, Areg[16*g + 4*q + 1], a);
        a = dot4(P.z, Areg[16*g + 4*q + 2], a);
        a = dot4(P.w, Areg[16*g + 4*q + 3], a);
      }
      float ex = (g == 0) ? e0 : (g == 1) ? e1 : (g == 2) ? e2 : e3;
      pr = fmaf((float)a, ex, pr);
    }
    if (h == 1) part[c] = pr;
    __syncthreads();                  // B2: partials ready

    // ---- combine + log (h=0) ----
    if (h == 0) {
      float r = (pr + part[c]) * cscale;
      alphaReg = __logf(r + 1e-16f) + mref + logE_cur;
      logE_cur = __logf(eNxt + 1e-16f);
      symNext  = symNN;
    }
  }

  // ---- outputs: alpha_T then loglik ----
  if (h == 0) out[(size_t)b * SDIM + c] = alphaReg;

  float mx = (h == 0) ? wave_max_f32(alphaReg) : NEG_BIG;
  if (h == 0 && (t & 63) == 0) red2[wv] = mx;
  __syncthreads();
  float mf = fmaxf(fmaxf(fmaxf(red2[0], red2[1]), fmaxf(red2[2], red2[3])),
                   fmaxf(fmaxf(red2[4], red2[5]), fmaxf(red2[6], red2[7])));

  float se = (h == 0) ? __expf(alphaReg - mf) : 0.f;
  #pragma unroll
  for (int off = 32; off; off >>= 1) se += __shfl_xor(se, off);
  __syncthreads();                    // red2 reads done before rewrite
  if (h == 0 && (t & 63) == 0) red2[wv] = se;
  __syncthreads();
  if (t == 0) {
    float tot = 0.f;
    #pragma unroll
    for (int k = 0; k < 8; ++k) tot += red2[k];
    out[(size_t)BSZ * SDIM + b] = __logf(tot + SDIM * 1e-16f) + mf;
  }
}

extern "C" void kernel_launch(void* const* d_in, const int* in_sizes, int n_in,
                              void* d_out, int out_size, void* d_ws, size_t ws_size,
                              hipStream_t stream) {
  const float* x  = (const float*)d_in[0];
  const float* A  = (const float*)d_in[1];
  const float* Bm = (const float*)d_in[2];
  float* out = (float*)d_out;

  uint8_t*  sym  = (uint8_t*)d_ws;                                  // 1 MB
  unsigned* Aq   = (unsigned*)((char*)d_ws + (1 << 20));            // 256 KB
  float*    cmax = (float*)((char*)d_ws + (1 << 20) + (256 << 10)); // 2 KB

  sym_kernel<<<(BSZ * TLEN) / 256, 256, 0, stream>>>(x, sym);
  colmax_kernel<<<SDIM, 64, 0, stream>>>(A, cmax);
  pack_kernel<<<(SDIM * 128) / 256, 256, 0, stream>>>(A, cmax, Aq);
  hmm_fwd<<<BSZ, 1024, 0, stream>>>(Aq, cmax, Bm, sym, out);
}

// Round 5
// 10954.487 us; speedup vs baseline: 1.0144x; 1.0144x over previous
//
#include <hip/hip_runtime.h>
#include <stdint.h>

#define BSZ  128
#define TLEN 8192
#define MDIM 64
#define SDIM 512
#define NEG_BIG (-1e30f)

// ---- 8-bit dot product: 4 MACs per instruction, exact i32 accumulation ----
#if __has_builtin(__builtin_amdgcn_udot4)
  #define QA 255
  __device__ __forceinline__ int dot4(unsigned a, unsigned b, int c) {
    return (int)__builtin_amdgcn_udot4(a, b, (unsigned)c, false);
  }
#elif __has_builtin(__builtin_amdgcn_sdot4)
  #define QA 127   // keep bytes in [0,127] so signed == unsigned
  __device__ __forceinline__ int dot4(unsigned a, unsigned b, int c) {
    return __builtin_amdgcn_sdot4((int)a, (int)b, c, false);
  }
#else
  #define QA 255
  __device__ __forceinline__ int dot4(unsigned a, unsigned b, int c) {
    c += (int)((a & 0xffu) * (b & 0xffu));
    c += (int)(((a >> 8) & 0xffu) * ((b >> 8) & 0xffu));
    c += (int)(((a >> 16) & 0xffu) * ((b >> 16) & 0xffu));
    c += (int)((a >> 24) * (b >> 24));
    return c;
  }
#endif

// Wave-wide (64-lane) max via DPP, no LDS. Verified R3/R4 (absmax 0).
__device__ __forceinline__ float wave_max_f32(float x) {
  int v = __builtin_bit_cast(int, x);
#define DPP_STEP(ctrl)                                                        \
  {                                                                           \
    int o = __builtin_amdgcn_update_dpp(v, v, ctrl, 0xf, 0xf, false);         \
    v = __builtin_bit_cast(int, fmaxf(__builtin_bit_cast(float, v),           \
                                      __builtin_bit_cast(float, o)));         \
  }
  DPP_STEP(0x111)  // row_shr:1
  DPP_STEP(0x112)  // row_shr:2
  DPP_STEP(0x114)  // row_shr:4
  DPP_STEP(0x118)  // row_shr:8
  DPP_STEP(0x142)  // row_bcast15
  DPP_STEP(0x143)  // row_bcast31 -> lane63 has max(0..63)
#undef DPP_STEP
  return __builtin_bit_cast(float, __builtin_amdgcn_readlane(v, 63));
}

// Extract symbol index from one-hot rows: sym[b,t] = argmax_m x[b,t,m]
__global__ void sym_kernel(const float* __restrict__ x, uint8_t* __restrict__ sym) {
  int i = blockIdx.x * blockDim.x + threadIdx.x;  // flat (b,t)
  const float4* p = (const float4*)(x + (size_t)i * MDIM);
  int idx = 0;
  #pragma unroll
  for (int j = 0; j < 16; ++j) {
    float4 v = p[j];
    if (v.x > 0.5f) idx = 4*j + 0;
    if (v.y > 0.5f) idx = 4*j + 1;
    if (v.z > 0.5f) idx = 4*j + 2;
    if (v.w > 0.5f) idx = 4*j + 3;
  }
  sym[i] = (uint8_t)idx;
}

// Per-column max of A (quantization scale). One 64-thread block per column.
__global__ void colmax_kernel(const float* __restrict__ A, float* __restrict__ cmax) {
  int c = blockIdx.x, l = threadIdx.x;
  float m = 0.f;
  for (int r = l; r < SDIM; r += 64) m = fmaxf(m, A[(size_t)r * SDIM + c]);
  #pragma unroll
  for (int off = 32; off; off >>= 1) m = fmaxf(m, __shfl_xor(m, off));
  if (l == 0) cmax[c] = m;
}

// Pack A column-major as u8 row-quads: Aq[c*128 + j] = A[4j..4j+3][c] scaled
__global__ void pack_kernel(const float* __restrict__ A, const float* __restrict__ cmax,
                            unsigned* __restrict__ Aq) {
  int id = blockIdx.x * 256 + threadIdx.x;   // 512*128 = 65536 ids
  int c = id >> 7, j = id & 127;
  float s = (float)QA / cmax[c];
  unsigned q = 0;
  #pragma unroll
  for (int bb = 0; bb < 4; ++bb) {
    float v = A[(size_t)(4 * j + bb) * SDIM + c];
    int qi = (int)(v * s + 0.5f);
    if (qi > QA) qi = QA;
    q |= (unsigned)qi << (8 * bb);
  }
  Aq[c * 128 + j] = q;
}

// One block per batch; 1024 threads. Thread (c = t&511, h = t>>9) owns
// column c rows [256h, 256h+256) as 16 NAMED uint4 (64 VGPRs — no arrays,
// so nothing can be exiled to scratch/AGPR-with-moves). h=0 threads also
// own state c's alpha. 2 barriers per step.
__global__ __launch_bounds__(1024, 4) void hmm_fwd(
    const unsigned* __restrict__ Aq, const float* __restrict__ cmax,
    const float* __restrict__ Bm, const uint8_t* __restrict__ sym,
    float* __restrict__ out) {
  const int b  = blockIdx.x;
  const int t  = threadIdx.x;
  const int c  = t & (SDIM - 1);
  const int h  = t >> 9;             // half 0/1: rows 256h..256h+255
  const int wv = t >> 6;             // wave 0..15

  __shared__ uint8_t p8[2][SDIM];    // quantized p, double-buffered
  __shared__ float   red[2][8];      // per-wave maxes (source waves 0..7)
  __shared__ float   part[SDIM];     // h=1 half-column partials (rescaled)
  __shared__ float   red2[8];

  // ---- A half-column: 16 named uint4 = 64 packed u8 quads in VGPRs ----
  const uint4* asrc = (const uint4*)(Aq + (size_t)c * 128 + 64 * h);
  uint4 A0  = asrc[0],  A1  = asrc[1],  A2  = asrc[2],  A3  = asrc[3];
  uint4 A4  = asrc[4],  A5  = asrc[5],  A6  = asrc[6],  A7  = asrc[7];
  uint4 A8  = asrc[8],  A9  = asrc[9],  A10 = asrc[10], A11 = asrc[11];
  uint4 A12 = asrc[12], A13 = asrc[13], A14 = asrc[14], A15 = asrc[15];

  const float cscale = cmax[c] * (1.0f / ((float)QA * (float)QA));
  const uint8_t* symb = sym + (size_t)b * TLEN;

  // ---- init: alpha0 = log(B[sym0,:]+eps) + [0,-inf,...] (h=0 only) ----
  float alphaReg = NEG_BIG;
  int   symNext  = 0;
  float logE_cur = 0.f;
  if (h == 0) {
    int s0 = symb[0];
    alphaReg = __logf(Bm[s0 * SDIM + c] + 1e-16f) + (c == 0 ? 0.f : NEG_BIG);
    symNext  = symb[1];
    logE_cur = __logf(Bm[symNext * SDIM + c] + 1e-16f);
    symNext  = symb[2];
  }

  for (int step = 1; step < TLEN; ++step) {
    const int par = step & 1;

    // ---- pre-B1: h=0 waves quantize their 64 states with wave-local max ----
    if (h == 0) {
      float m_w = wave_max_f32(alphaReg);
      float p   = __expf(alphaReg - m_w);
      p8[par][c] = (uint8_t)(p * (float)QA + 0.5f);
      if ((t & 63) == 0) red[par][wv] = m_w;
    }
    __syncthreads();                  // B1: p8 + red ready

    // emission prefetch (h=0), latency hides under dot phase
    float eNxt = 0.f; int symNN = 0;
    if (h == 0) {
      eNxt  = Bm[symNext * SDIM + c];
      symNN = symb[(step + 2 <= TLEN - 1) ? step + 2 : TLEN - 1];
    }

    float4 ra = *(const float4*)&red[par][0];
    float4 rb = *(const float4*)&red[par][4];
    float mref = fmaxf(fmaxf(fmaxf(ra.x, ra.y), fmaxf(ra.z, ra.w)),
                       fmaxf(fmaxf(rb.x, rb.y), fmaxf(rb.z, rb.w)));
    // rescale factors for this half's 4 source waves
    float e0, e1, e2, e3;
    if (h == 0) { e0 = __expf(ra.x - mref); e1 = __expf(ra.y - mref);
                  e2 = __expf(ra.z - mref); e3 = __expf(ra.w - mref); }
    else        { e0 = __expf(rb.x - mref); e1 = __expf(rb.y - mref);
                  e2 = __expf(rb.z - mref); e3 = __expf(rb.w - mref); }

    // ---- dot: 64 dot4, fully explicit operands, 4 per-source-wave accs ----
    const uint32_t* pw = (const uint32_t*)p8[par] + 64 * h;  // wave-uniform
    float pr = 0.f;
    {
      uint4 P0, P1, P2, P3; int a;
#define GRP(OFS, Qa, Qb, Qc, Qd, EG)                                          \
      P0 = *(const uint4*)(pw + (OFS));      P1 = *(const uint4*)(pw + (OFS) + 4);  \
      P2 = *(const uint4*)(pw + (OFS) + 8);  P3 = *(const uint4*)(pw + (OFS) + 12); \
      a = 0;                                                                  \
      a = dot4(P0.x, Qa.x, a); a = dot4(P0.y, Qa.y, a);                       \
      a = dot4(P0.z, Qa.z, a); a = dot4(P0.w, Qa.w, a);                       \
      a = dot4(P1.x, Qb.x, a); a = dot4(P1.y, Qb.y, a);                       \
      a = dot4(P1.z, Qb.z, a); a = dot4(P1.w, Qb.w, a);                       \
      a = dot4(P2.x, Qc.x, a); a = dot4(P2.y, Qc.y, a);                       \
      a = dot4(P2.z, Qc.z, a); a = dot4(P2.w, Qc.w, a);                       \
      a = dot4(P3.x, Qd.x, a); a = dot4(P3.y, Qd.y, a);                       \
      a = dot4(P3.z, Qd.z, a); a = dot4(P3.w, Qd.w, a);                       \
      pr = fmaf((float)a, (EG), pr);
      GRP(0,  A0,  A1,  A2,  A3,  e0)
      GRP(16, A4,  A5,  A6,  A7,  e1)
      GRP(32, A8,  A9,  A10, A11, e2)
      GRP(48, A12, A13, A14, A15, e3)
#undef GRP
    }
    if (h == 1) part[c] = pr;
    __syncthreads();                  // B2: partials ready

    // ---- combine + log (h=0) ----
    if (h == 0) {
      float r = (pr + part[c]) * cscale;
      alphaReg = __logf(r + 1e-16f) + mref + logE_cur;
      logE_cur = __logf(eNxt + 1e-16f);
      symNext  = symNN;
    }
  }

  // ---- outputs: alpha_T then loglik ----
  if (h == 0) out[(size_t)b * SDIM + c] = alphaReg;

  float mx = (h == 0) ? wave_max_f32(alphaReg) : NEG_BIG;
  if (h == 0 && (t & 63) == 0) red2[wv] = mx;
  __syncthreads();
  float mf = fmaxf(fmaxf(fmaxf(red2[0], red2[1]), fmaxf(red2[2], red2[3])),
                   fmaxf(fmaxf(red2[4], red2[5]), fmaxf(red2[6], red2[7])));

  float se = (h == 0) ? __expf(alphaReg - mf) : 0.f;
  #pragma unroll
  for (int off = 32; off; off >>= 1) se += __shfl_xor(se, off);
  __syncthreads();                    // red2 reads done before rewrite
  if (h == 0 && (t & 63) == 0) red2[wv] = se;
  __syncthreads();
  if (t == 0) {
    float tot = 0.f;
    #pragma unroll
    for (int k = 0; k < 8; ++k) tot += red2[k];
    out[(size_t)BSZ * SDIM + b] = __logf(tot + SDIM * 1e-16f) + mf;
  }
}

extern "C" void kernel_launch(void* const* d_in, const int* in_sizes, int n_in,
                              void* d_out, int out_size, void* d_ws, size_t ws_size,
                              hipStream_t stream) {
  const float* x  = (const float*)d_in[0];
  const float* A  = (const float*)d_in[1];
  const float* Bm = (const float*)d_in[2];
  float* out = (float*)d_out;

  uint8_t*  sym  = (uint8_t*)d_ws;                                  // 1 MB
  unsigned* Aq   = (unsigned*)((char*)d_ws + (1 << 20));            // 256 KB
  float*    cmax = (float*)((char*)d_ws + (1 << 20) + (256 << 10)); // 2 KB

  sym_kernel<<<(BSZ * TLEN) / 256, 256, 0, stream>>>(x, sym);
  colmax_kernel<<<SDIM, 64, 0, stream>>>(A, cmax);
  pack_kernel<<<(SDIM * 128) / 256, 256, 0, stream>>>(A, cmax, Aq);
  hmm_fwd<<<BSZ, 1024, 0, stream>>>(Aq, cmax, Bm, sym, out);
}

// Round 6
// 10352.291 us; speedup vs baseline: 1.0735x; 1.0582x over previous
//
#include <hip/hip_runtime.h>
#include <stdint.h>

#define BSZ  128
#define TLEN 8192
#define MDIM 64
#define SDIM 512
#define NEG_BIG (-1e30f)

// ---- 8-bit dot product: 4 MACs per instruction, exact i32 accumulation ----
#if __has_builtin(__builtin_amdgcn_udot4)
  #define QA 255
  __device__ __forceinline__ int dot4(unsigned a, unsigned b, int c) {
    return (int)__builtin_amdgcn_udot4(a, b, (unsigned)c, false);
  }
#elif __has_builtin(__builtin_amdgcn_sdot4)
  #define QA 127   // keep bytes in [0,127] so signed == unsigned
  __device__ __forceinline__ int dot4(unsigned a, unsigned b, int c) {
    return __builtin_amdgcn_sdot4((int)a, (int)b, c, false);
  }
#else
  #define QA 255
  __device__ __forceinline__ int dot4(unsigned a, unsigned b, int c) {
    c += (int)((a & 0xffu) * (b & 0xffu));
    c += (int)(((a >> 8) & 0xffu) * ((b >> 8) & 0xffu));
    c += (int)(((a >> 16) & 0xffu) * ((b >> 16) & 0xffu));
    c += (int)((a >> 24) * (b >> 24));
    return c;
  }
#endif

// Wave-wide (64-lane) max via DPP, no LDS. Verified R3-R5 (absmax 0).
__device__ __forceinline__ float wave_max_f32(float x) {
  int v = __builtin_bit_cast(int, x);
#define DPP_STEP(ctrl)                                                        \
  {                                                                           \
    int o = __builtin_amdgcn_update_dpp(v, v, ctrl, 0xf, 0xf, false);         \
    v = __builtin_bit_cast(int, fmaxf(__builtin_bit_cast(float, v),           \
                                      __builtin_bit_cast(float, o)));         \
  }
  DPP_STEP(0x111)  // row_shr:1
  DPP_STEP(0x112)  // row_shr:2
  DPP_STEP(0x114)  // row_shr:4
  DPP_STEP(0x118)  // row_shr:8
  DPP_STEP(0x142)  // row_bcast15
  DPP_STEP(0x143)  // row_bcast31 -> lane63 has max(0..63)
#undef DPP_STEP
  return __builtin_bit_cast(float, __builtin_amdgcn_readlane(v, 63));
}

// Extract symbol index from one-hot rows: sym[b,t] = argmax_m x[b,t,m]
__global__ void sym_kernel(const float* __restrict__ x, uint8_t* __restrict__ sym) {
  int i = blockIdx.x * blockDim.x + threadIdx.x;  // flat (b,t)
  const float4* p = (const float4*)(x + (size_t)i * MDIM);
  int idx = 0;
  #pragma unroll
  for (int j = 0; j < 16; ++j) {
    float4 v = p[j];
    if (v.x > 0.5f) idx = 4*j + 0;
    if (v.y > 0.5f) idx = 4*j + 1;
    if (v.z > 0.5f) idx = 4*j + 2;
    if (v.w > 0.5f) idx = 4*j + 3;
  }
  sym[i] = (uint8_t)idx;
}

// Per-column max of A (quantization scale). One 64-thread block per column.
__global__ void colmax_kernel(const float* __restrict__ A, float* __restrict__ cmax) {
  int c = blockIdx.x, l = threadIdx.x;
  float m = 0.f;
  for (int r = l; r < SDIM; r += 64) m = fmaxf(m, A[(size_t)r * SDIM + c]);
  #pragma unroll
  for (int off = 32; off; off >>= 1) m = fmaxf(m, __shfl_xor(m, off));
  if (l == 0) cmax[c] = m;
}

// Pack A column-major as u8 row-quads: Aq[c*128 + j] = A[4j..4j+3][c] scaled
__global__ void pack_kernel(const float* __restrict__ A, const float* __restrict__ cmax,
                            unsigned* __restrict__ Aq) {
  int id = blockIdx.x * 256 + threadIdx.x;   // 512*128 = 65536 ids
  int c = id >> 7, j = id & 127;
  float s = (float)QA / cmax[c];
  unsigned q = 0;
  #pragma unroll
  for (int bb = 0; bb < 4; ++bb) {
    float v = A[(size_t)(4 * j + bb) * SDIM + c];
    int qi = (int)(v * s + 0.5f);
    if (qi > QA) qi = QA;
    q |= (unsigned)qi << (8 * bb);
  }
  Aq[c * 128 + j] = q;
}

// One block per batch; 1024 threads. Thread (c = t&511, h = t>>9) owns
// column c rows [256h, 256h+256) as 64 u8-quad words FORCED into VGPRs:
// an asm "+v" keep-alive makes the loaded values register-defined (no
// memory home), so the compiler cannot rematerialize the loads inside
// the loop (the R2-R5 failure mode: ~25 TB/s of L2 re-reads of A).
__global__ __launch_bounds__(1024, 4) void hmm_fwd(
    const unsigned* __restrict__ Aq, const float* __restrict__ cmax,
    const float* __restrict__ Bm, const uint8_t* __restrict__ sym,
    float* __restrict__ out) {
  const int b  = blockIdx.x;
  const int t  = threadIdx.x;
  const int c  = t & (SDIM - 1);
  const int h  = t >> 9;             // half 0/1: rows 256h..256h+255
  const int wv = t >> 6;             // wave 0..15

  __shared__ uint8_t p8[2][SDIM];    // quantized p, double-buffered
  __shared__ float   red[2][8];      // per-wave maxes (source waves 0..7)
  __shared__ float   part[SDIM];     // h=1 half-column partials (rescaled)
  __shared__ float   red2[8];

  // ---- A half-column: 64 scalar words, then keep-alive pins them ----
  unsigned w00,w01,w02,w03,w04,w05,w06,w07,w08,w09,w10,w11,w12,w13,w14,w15,
           w16,w17,w18,w19,w20,w21,w22,w23,w24,w25,w26,w27,w28,w29,w30,w31,
           w32,w33,w34,w35,w36,w37,w38,w39,w40,w41,w42,w43,w44,w45,w46,w47,
           w48,w49,w50,w51,w52,w53,w54,w55,w56,w57,w58,w59,w60,w61,w62,w63;
  {
    const uint4* asrc = (const uint4*)(Aq + (size_t)c * 128 + 64 * h);
    uint4 v;
    v=asrc[0];  w00=v.x; w01=v.y; w02=v.z; w03=v.w;
    v=asrc[1];  w04=v.x; w05=v.y; w06=v.z; w07=v.w;
    v=asrc[2];  w08=v.x; w09=v.y; w10=v.z; w11=v.w;
    v=asrc[3];  w12=v.x; w13=v.y; w14=v.z; w15=v.w;
    v=asrc[4];  w16=v.x; w17=v.y; w18=v.z; w19=v.w;
    v=asrc[5];  w20=v.x; w21=v.y; w22=v.z; w23=v.w;
    v=asrc[6];  w24=v.x; w25=v.y; w26=v.z; w27=v.w;
    v=asrc[7];  w28=v.x; w29=v.y; w30=v.z; w31=v.w;
    v=asrc[8];  w32=v.x; w33=v.y; w34=v.z; w35=v.w;
    v=asrc[9];  w36=v.x; w37=v.y; w38=v.z; w39=v.w;
    v=asrc[10]; w40=v.x; w41=v.y; w42=v.z; w43=v.w;
    v=asrc[11]; w44=v.x; w45=v.y; w46=v.z; w47=v.w;
    v=asrc[12]; w48=v.x; w49=v.y; w50=v.z; w51=v.w;
    v=asrc[13]; w52=v.x; w53=v.y; w54=v.z; w55=v.w;
    v=asrc[14]; w56=v.x; w57=v.y; w58=v.z; w59=v.w;
    v=asrc[15]; w60=v.x; w61=v.y; w62=v.z; w63=v.w;
  }
  // Nominal write => memory copy is stale => no remat possible.
  asm volatile("" : "+v"(w00),"+v"(w01),"+v"(w02),"+v"(w03),
                    "+v"(w04),"+v"(w05),"+v"(w06),"+v"(w07),
                    "+v"(w08),"+v"(w09),"+v"(w10),"+v"(w11),
                    "+v"(w12),"+v"(w13),"+v"(w14),"+v"(w15));
  asm volatile("" : "+v"(w16),"+v"(w17),"+v"(w18),"+v"(w19),
                    "+v"(w20),"+v"(w21),"+v"(w22),"+v"(w23),
                    "+v"(w24),"+v"(w25),"+v"(w26),"+v"(w27),
                    "+v"(w28),"+v"(w29),"+v"(w30),"+v"(w31));
  asm volatile("" : "+v"(w32),"+v"(w33),"+v"(w34),"+v"(w35),
                    "+v"(w36),"+v"(w37),"+v"(w38),"+v"(w39),
                    "+v"(w40),"+v"(w41),"+v"(w42),"+v"(w43),
                    "+v"(w44),"+v"(w45),"+v"(w46),"+v"(w47));
  asm volatile("" : "+v"(w48),"+v"(w49),"+v"(w50),"+v"(w51),
                    "+v"(w52),"+v"(w53),"+v"(w54),"+v"(w55),
                    "+v"(w56),"+v"(w57),"+v"(w58),"+v"(w59),
                    "+v"(w60),"+v"(w61),"+v"(w62),"+v"(w63));

  const float cscale = cmax[c] * (1.0f / ((float)QA * (float)QA));
  const uint8_t* symb = sym + (size_t)b * TLEN;

  // ---- init: alpha0 = log(B[sym0,:]+eps) + [0,-inf,...] (h=0 only) ----
  float alphaReg = NEG_BIG;
  int   symNext  = 0;
  float logE_cur = 0.f;
  if (h == 0) {
    int s0 = symb[0];
    alphaReg = __logf(Bm[s0 * SDIM + c] + 1e-16f) + (c == 0 ? 0.f : NEG_BIG);
    symNext  = symb[1];
    logE_cur = __logf(Bm[symNext * SDIM + c] + 1e-16f);
    symNext  = symb[2];
  }

  for (int step = 1; step < TLEN; ++step) {
    const int par = step & 1;

    // ---- pre-B1: h=0 waves quantize their 64 states with wave-local max ----
    if (h == 0) {
      float m_w = wave_max_f32(alphaReg);
      float p   = __expf(alphaReg - m_w);
      p8[par][c] = (uint8_t)(p * (float)QA + 0.5f);
      if ((t & 63) == 0) red[par][wv] = m_w;
    }
    __syncthreads();                  // B1: p8 + red ready

    // emission prefetch (h=0), latency hides under dot phase
    float eNxt = 0.f; int symNN = 0;
    if (h == 0) {
      eNxt  = Bm[symNext * SDIM + c];
      symNN = symb[(step + 2 <= TLEN - 1) ? step + 2 : TLEN - 1];
    }

    float4 ra = *(const float4*)&red[par][0];
    float4 rb = *(const float4*)&red[par][4];
    float mref = fmaxf(fmaxf(fmaxf(ra.x, ra.y), fmaxf(ra.z, ra.w)),
                       fmaxf(fmaxf(rb.x, rb.y), fmaxf(rb.z, rb.w)));
    // rescale factors for this half's 4 source waves
    float e0, e1, e2, e3;
    if (h == 0) { e0 = __expf(ra.x - mref); e1 = __expf(ra.y - mref);
                  e2 = __expf(ra.z - mref); e3 = __expf(ra.w - mref); }
    else        { e0 = __expf(rb.x - mref); e1 = __expf(rb.y - mref);
                  e2 = __expf(rb.z - mref); e3 = __expf(rb.w - mref); }

    // ---- dot: 64 dot4 on pinned registers, 4 per-source-wave accs ----
    const uint32_t* pw = (const uint32_t*)p8[par] + 64 * h;  // wave-uniform
    float pr = 0.f;
    {
      uint4 P0, P1, P2, P3; int a;
#define GRP(OFS, W0,W1,W2,W3,W4,W5,W6,W7,W8,W9,Wa,Wb,Wc,Wd,We,Wf, EG)        \
      P0 = *(const uint4*)(pw + (OFS));      P1 = *(const uint4*)(pw + (OFS) + 4);  \
      P2 = *(const uint4*)(pw + (OFS) + 8);  P3 = *(const uint4*)(pw + (OFS) + 12); \
      a = 0;                                                                  \
      a = dot4(P0.x, W0, a); a = dot4(P0.y, W1, a);                           \
      a = dot4(P0.z, W2, a); a = dot4(P0.w, W3, a);                           \
      a = dot4(P1.x, W4, a); a = dot4(P1.y, W5, a);                           \
      a = dot4(P1.z, W6, a); a = dot4(P1.w, W7, a);                           \
      a = dot4(P2.x, W8, a); a = dot4(P2.y, W9, a);                           \
      a = dot4(P2.z, Wa, a); a = dot4(P2.w, Wb, a);                           \
      a = dot4(P3.x, Wc, a); a = dot4(P3.y, Wd, a);                           \
      a = dot4(P3.z, We, a); a = dot4(P3.w, Wf, a);                           \
      pr = fmaf((float)a, (EG), pr);
      GRP(0,  w00,w01,w02,w03,w04,w05,w06,w07,w08,w09,w10,w11,w12,w13,w14,w15, e0)
      GRP(16, w16,w17,w18,w19,w20,w21,w22,w23,w24,w25,w26,w27,w28,w29,w30,w31, e1)
      GRP(32, w32,w33,w34,w35,w36,w37,w38,w39,w40,w41,w42,w43,w44,w45,w46,w47, e2)
      GRP(48, w48,w49,w50,w51,w52,w53,w54,w55,w56,w57,w58,w59,w60,w61,w62,w63, e3)
#undef GRP
    }
    if (h == 1) part[c] = pr;
    __syncthreads();                  // B2: partials ready

    // ---- combine + log (h=0) ----
    if (h == 0) {
      float r = (pr + part[c]) * cscale;
      alphaReg = __logf(r + 1e-16f) + mref + logE_cur;
      logE_cur = __logf(eNxt + 1e-16f);
      symNext  = symNN;
    }
  }

  // ---- outputs: alpha_T then loglik ----
  if (h == 0) out[(size_t)b * SDIM + c] = alphaReg;

  float mx = (h == 0) ? wave_max_f32(alphaReg) : NEG_BIG;
  if (h == 0 && (t & 63) == 0) red2[wv] = mx;
  __syncthreads();
  float mf = fmaxf(fmaxf(fmaxf(red2[0], red2[1]), fmaxf(red2[2], red2[3])),
                   fmaxf(fmaxf(red2[4], red2[5]), fmaxf(red2[6], red2[7])));

  float se = (h == 0) ? __expf(alphaReg - mf) : 0.f;
  #pragma unroll
  for (int off = 32; off; off >>= 1) se += __shfl_xor(se, off);
  __syncthreads();                    // red2 reads done before rewrite
  if (h == 0 && (t & 63) == 0) red2[wv] = se;
  __syncthreads();
  if (t == 0) {
    float tot = 0.f;
    #pragma unroll
    for (int k = 0; k < 8; ++k) tot += red2[k];
    out[(size_t)BSZ * SDIM + b] = __logf(tot + SDIM * 1e-16f) + mf;
  }
}

extern "C" void kernel_launch(void* const* d_in, const int* in_sizes, int n_in,
                              void* d_out, int out_size, void* d_ws, size_t ws_size,
                              hipStream_t stream) {
  const float* x  = (const float*)d_in[0];
  const float* A  = (const float*)d_in[1];
  const float* Bm = (const float*)d_in[2];
  float* out = (float*)d_out;

  uint8_t*  sym  = (uint8_t*)d_ws;                                  // 1 MB
  unsigned* Aq   = (unsigned*)((char*)d_ws + (1 << 20));            // 256 KB
  float*    cmax = (float*)((char*)d_ws + (1 << 20) + (256 << 10)); // 2 KB

  sym_kernel<<<(BSZ * TLEN) / 256, 256, 0, stream>>>(x, sym);
  colmax_kernel<<<SDIM, 64, 0, stream>>>(A, cmax);
  pack_kernel<<<(SDIM * 128) / 256, 256, 0, stream>>>(A, cmax, Aq);
  hmm_fwd<<<BSZ, 1024, 0, stream>>>(Aq, cmax, Bm, sym, out);
}